// Round 1
// 276.015 us; speedup vs baseline: 1.0813x; 1.0813x over previous
//
#include <hip/hip_runtime.h>

#define L_DIM 1024
#define B_DIM 16
#define D_DIM 1024
#define K_DIM 1024            // = D
#define N_DIM 3072            // = 3*D
#define M_DIM (L_DIM * B_DIM) // 16384
#define CHAINS 16384          // B*D
#define CHUNK 64              // steps per chunk
#define NCHUNK 16             // L / CHUNK

typedef float f32x4 __attribute__((ext_vector_type(4)));
typedef __bf16 bf16x8 __attribute__((ext_vector_type(8)));
typedef unsigned short u16;
typedef unsigned int u32;

__device__ __forceinline__ u16 f2bf(float f) {
  u32 u = __float_as_uint(f);
  u = u + 0x7FFFu + ((u >> 16) & 1u);   // round-to-nearest-even
  return (u16)(u >> 16);
}
__device__ __forceinline__ float bf2f(u16 v) {
  return __uint_as_float(((u32)v) << 16);
}
__device__ __forceinline__ float fexp(float v) {
  return __builtin_amdgcn_exp2f(v * 1.4426950408889634f);
}
__device__ __forceinline__ float sigm(float z) {
  return __builtin_amdgcn_rcpf(1.0f + fexp(-z));
}
__device__ __forceinline__ float ftanh(float v) {
  return 1.0f - 2.0f * __builtin_amdgcn_rcpf(1.0f + fexp(2.0f * v));
}

// ---------------- x: fp32 -> bf16 straight cast ----------------
__global__ __launch_bounds__(256) void cvt_x_kernel(const float4* __restrict__ in,
                                                    ushort4* __restrict__ out, int n4) {
  int i = blockIdx.x * 256 + threadIdx.x;
  if (i < n4) {
    float4 v = in[i];
    ushort4 o;
    o.x = f2bf(v.x); o.y = f2bf(v.y); o.z = f2bf(v.z); o.w = f2bf(v.w);
    out[i] = o;
  }
}

// ---------------- W (K x N fp32) -> Wt (N' x K bf16), plane-major N permute ----------------
__global__ __launch_bounds__(256) void cvt_w_kernel(const float* __restrict__ W,
                                                    u16* __restrict__ Wt) {
  __shared__ float tile[64][65];
  int c0 = blockIdx.x * 64;  // N block
  int r0 = blockIdx.y * 64;  // K block
  int tx = threadIdx.x & 63;
  int ty = threadIdx.x >> 6;
#pragma unroll
  for (int i = 0; i < 16; ++i) {
    int row = i * 4 + ty;
    tile[row][tx] = W[(size_t)(r0 + row) * N_DIM + c0 + tx];
  }
  __syncthreads();
#pragma unroll
  for (int i = 0; i < 16; ++i) {
    int crow = i * 4 + ty;
    int c = c0 + crow;
    int nprime = (c % 3) * D_DIM + (c / 3);
    Wt[(size_t)nprime * K_DIM + r0 + tx] = f2bf(tile[tx][crow]);
  }
}

// ---------------- GEMM: 256x256 tile, BK=64, 8-phase counted-vmcnt schedule ----------------
// U(M x N bf16) = A(M x K bf16) @ Bt(N x K bf16)^T.
// 8 waves (2M x 4N), per-wave 128x64 output, acc[8][4] f32x4.
// LDS 128 KiB: A[2 buf][256 rows][64 k] at 0, B same at +32768 (u16 units).
// Half-tile (HT) = 128 rows = 8192 u16 = 16 KiB; staged linearly by global_load_lds
// (512 thr x 16 B x 2). T2 swizzle: LDS[row][slot'] holds k-slot slot'^(row&7)
// (slot = 8 bf16 = 16 B); stage pre-swizzles the GLOBAL source, reads XOR the address.
// Stage schedule (iteration u, buf=u&1, nb=buf^1):
//   g1: stage A-HT0[u+1]->nb   g2: stage A-HT1[u+1]->nb
//   g3: stage B-HT0[u+2]->buf  g4: stage B-HT1[u+2]->buf, then vmcnt(4)
// One counted vmcnt per K-tile; raw s_barrier pairs per phase; setprio around MFMA.

#define AS1 __attribute__((address_space(1)))
#define AS3 __attribute__((address_space(3)))
#define STAGE(gp, lp) do { \
  __builtin_amdgcn_global_load_lds((const AS1 void*)(gp), (AS3 void*)(lp), 16, 0, 0); \
  __builtin_amdgcn_global_load_lds((const AS1 void*)((gp) + (size_t)64 * K_DIM), \
                                   (AS3 void*)((lp) + 4096), 16, 0, 0); \
} while (0)

#define QUAD(AI, JB, BF) \
  _Pragma("unroll") \
  for (int i = 0; i < 4; ++i) { \
    _Pragma("unroll") \
    for (int j = 0; j < 2; ++j) { \
      acc[AI + i][JB + j] = __builtin_amdgcn_mfma_f32_16x16x32_bf16(aF[i][0], BF[j][0], acc[AI + i][JB + j], 0, 0, 0); \
      acc[AI + i][JB + j] = __builtin_amdgcn_mfma_f32_16x16x32_bf16(aF[i][1], BF[j][1], acc[AI + i][JB + j], 0, 0, 0); \
    } \
  }

__global__ __launch_bounds__(512, 2) void gemm_kernel(const u16* __restrict__ A,
                                                      const u16* __restrict__ Bt,
                                                      u16* __restrict__ U) {
  __shared__ __align__(16) u16 sm[65536];   // 128 KiB
  const int tid = threadIdx.x;
  const int wave = tid >> 6;
  const int lane = tid & 63;
  const int wm = wave >> 2;        // 0..1  (M)
  const int wn = wave & 3;         // 0..3  (N)
  const int quad = lane >> 4;
  const int l16 = lane & 15;

  // XCD-aware bijective swizzle: 768 blocks, 96 per XCD = 8 contiguous M-rows x 12 N.
  const int flat = blockIdx.y * 12 + blockIdx.x;
  const int swz = (flat & 7) * 96 + (flat >> 3);
  const int m0 = (swz / 12) * 256;
  const int n0 = (swz % 12) * 256;

  // staging source (per-thread): thread t covers HT rows rr and rr+64, 16 B each,
  // global k-slot pre-swizzled so linear LDS dest yields swizzled content.
  const int rr = tid >> 3;                      // 0..63
  const int slot = (tid & 7) ^ (rr & 7);
  const u16* gA = A + (size_t)(m0 + rr) * K_DIM + slot * 8;
  const u16* gB = Bt + (size_t)(n0 + rr) * K_DIM + slot * 8;

  // LDS stage dest bases (u16 units); HW adds lane*16 B.
  u16* ldsA = sm + wave * 512;
  u16* ldsB = sm + 32768 + wave * 512;

  // fragment read bases (swizzled column offsets)
  const int swzu = (l16 & 7) << 3;              // u16 units
  const int c0 = (quad * 8) ^ swzu;             // ks=0
  const int c1 = (32 + quad * 8) ^ swzu;        // ks=1
  const u16* pA = sm + (wm * 128 + l16) * 64;
  const u16* pB = sm + 32768 + (wn * 64 + l16) * 64;

  f32x4 acc[8][4] = {};

  // prologue: K-tile 0 fully -> buf0; B half-tiles of K-tile 1 -> buf1
  STAGE(gA, ldsA);                                   // A kt0 HT0
  STAGE(gA + (size_t)128 * K_DIM, ldsA + 8192);      // A kt0 HT1
  STAGE(gB, ldsB);                                   // B kt0 HT0
  STAGE(gB + (size_t)128 * K_DIM, ldsB + 8192);      // B kt0 HT1
  STAGE(gB + 64, ldsB + 16384);                      // B kt1 HT0
  STAGE(gB + (size_t)128 * K_DIM + 64, ldsB + 16384 + 8192); // B kt1 HT1
  asm volatile("s_waitcnt vmcnt(0)" ::: "memory");
  __builtin_amdgcn_s_barrier();

  for (int u = 0; u < 16; ++u) {
    const int buf = u & 1;
    const int nb = buf ^ 1;
    const u16* pAb = pA + buf * 16384;
    const u16* pBb = pB + buf * 16384;
    bf16x8 aF[4][2], bLo[2][2], bHi[2][2];

    // ---- phase 1: Q(0,0)  [reads A mt0-3 + B nt0-1; stage A-HT0[u+1]] ----
#pragma unroll
    for (int i = 0; i < 4; ++i) {
      aF[i][0] = *(const bf16x8*)(pAb + i * 1024 + c0);
      aF[i][1] = *(const bf16x8*)(pAb + i * 1024 + c1);
    }
#pragma unroll
    for (int j = 0; j < 2; ++j) {
      bLo[j][0] = *(const bf16x8*)(pBb + j * 1024 + c0);
      bLo[j][1] = *(const bf16x8*)(pBb + j * 1024 + c1);
    }
    if (u < 15) STAGE(gA + (u + 1) * 64, ldsA + nb * 16384);
    __builtin_amdgcn_s_barrier();
    __builtin_amdgcn_s_setprio(1);
    QUAD(0, 0, bLo)
    __builtin_amdgcn_s_setprio(0);
    __builtin_amdgcn_s_barrier();

    // ---- phase 2: Q(0,1)  [reads B nt2-3; stage A-HT1[u+1]] ----
#pragma unroll
    for (int j = 0; j < 2; ++j) {
      bHi[j][0] = *(const bf16x8*)(pBb + (2 + j) * 1024 + c0);
      bHi[j][1] = *(const bf16x8*)(pBb + (2 + j) * 1024 + c1);
    }
    if (u < 15) STAGE(gA + (size_t)128 * K_DIM + (u + 1) * 64, ldsA + nb * 16384 + 8192);
    __builtin_amdgcn_s_barrier();
    __builtin_amdgcn_s_setprio(1);
    QUAD(0, 2, bHi)
    __builtin_amdgcn_s_setprio(0);
    __builtin_amdgcn_s_barrier();

    // ---- phase 3: Q(1,1)  [reads A mt4-7; stage B-HT0[u+2]] ----
#pragma unroll
    for (int i = 0; i < 4; ++i) {
      aF[i][0] = *(const bf16x8*)(pAb + (4 + i) * 1024 + c0);
      aF[i][1] = *(const bf16x8*)(pAb + (4 + i) * 1024 + c1);
    }
    if (u < 14) STAGE(gB + (u + 2) * 64, ldsB + buf * 16384);
    __builtin_amdgcn_s_barrier();
    __builtin_amdgcn_s_setprio(1);
    QUAD(4, 2, bHi)
    __builtin_amdgcn_s_setprio(0);
    __builtin_amdgcn_s_barrier();

    // ---- phase 4: Q(1,0)  [stage B-HT1[u+2]; counted vmcnt] ----
    if (u < 14) {
      STAGE(gB + (size_t)128 * K_DIM + (u + 2) * 64, ldsB + buf * 16384 + 8192);
      asm volatile("s_waitcnt vmcnt(4)" ::: "memory");
    } else if (u == 14) {
      asm volatile("s_waitcnt vmcnt(0)" ::: "memory");
    }
    __builtin_amdgcn_s_barrier();
    __builtin_amdgcn_s_setprio(1);
    QUAD(4, 0, bLo)
    __builtin_amdgcn_s_setprio(0);
    __builtin_amdgcn_s_barrier();
  }

  // epilogue: C/D layout col=lane&15, row=(lane>>4)*4+r
#pragma unroll
  for (int i = 0; i < 8; ++i) {
#pragma unroll
    for (int j = 0; j < 4; ++j) {
      const int col = n0 + wn * 64 + j * 16 + l16;
      const int rb = m0 + wm * 128 + i * 16 + quad * 4;
#pragma unroll
      for (int r = 0; r < 4; ++r)
        U[(size_t)(rb + r) * N_DIM + col] = f2bf(acc[i][j][r]);
    }
  }
}

// ---------------- SRU chunked affine scan ----------------
__global__ __launch_bounds__(256) void sru_phase1(const u16* __restrict__ U,
                                                  const float* __restrict__ bias,
                                                  float* __restrict__ Aarr,
                                                  float* __restrict__ Barr) {
  int tid = blockIdx.x * 256 + threadIdx.x;   // = j*CHAINS + chain
  int chain = tid & (CHAINS - 1);
  int j = tid >> 14;
  int d = chain & (D_DIM - 1);
  int b = chain >> 10;
  float bb1 = bias[d];
  const u16* p = U + (size_t)(j * CHUNK * B_DIM + b) * N_DIM + d;
  float A = 1.0f, Bv = 0.0f;
#pragma unroll 4
  for (int s = 0; s < CHUNK; ++s) {
    float u0 = bf2f(p[0]);
    float g1 = sigm(bf2f(p[D_DIM]) + bb1);
    Bv = (Bv - u0) * g1 + u0;   // B <- g1*B + u0*(1-g1)
    A *= g1;
    p += (size_t)B_DIM * N_DIM;
  }
  Aarr[tid] = A;
  Barr[tid] = Bv;
}

__global__ __launch_bounds__(256) void sru_phase2(const float* __restrict__ Aarr,
                                                  const float* __restrict__ Barr,
                                                  const float* __restrict__ c0,
                                                  float* __restrict__ Cin,
                                                  float* __restrict__ clast) {
  int chain = blockIdx.x * 256 + threadIdx.x;
  float As[NCHUNK], Bs[NCHUNK];
#pragma unroll
  for (int j = 0; j < NCHUNK; ++j) {
    As[j] = Aarr[j * CHAINS + chain];
    Bs[j] = Barr[j * CHAINS + chain];
  }
  float c = c0[chain];
#pragma unroll
  for (int j = 0; j < NCHUNK; ++j) {
    Cin[j * CHAINS + chain] = c;
    c = As[j] * c + Bs[j];
  }
  clast[chain] = c;
}

__global__ __launch_bounds__(256) void sru_phase3(const u16* __restrict__ U,
                                                  const float* __restrict__ x,
                                                  const float* __restrict__ bias,
                                                  const float* __restrict__ Cin,
                                                  float* __restrict__ h) {
  int tid = blockIdx.x * 256 + threadIdx.x;
  int chain = tid & (CHAINS - 1);
  int j = tid >> 14;
  int d = chain & (D_DIM - 1);
  int b = chain >> 10;
  float bb1 = bias[d];
  float bb2 = bias[D_DIM + d];
  float c = Cin[tid];
  size_t m0 = (size_t)(j * CHUNK * B_DIM + b);
  const u16* p = U + m0 * N_DIM + d;
  const float* xp = x + m0 * D_DIM + d;
  float* hp = h + m0 * D_DIM + d;
#pragma unroll 4
  for (int s = 0; s < CHUNK; ++s) {
    float u0 = bf2f(p[0]);
    float g1 = sigm(bf2f(p[D_DIM]) + bb1);
    float g2 = sigm(bf2f(p[2 * D_DIM]) + bb2);
    c = (c - u0) * g1 + u0;
    float xv = *xp;
    *hp = (ftanh(c) - xv) * g2 + xv;
    p += (size_t)B_DIM * N_DIM;
    xp += B_DIM * D_DIM;
    hp += B_DIM * D_DIM;
  }
}

extern "C" void kernel_launch(void* const* d_in, const int* in_sizes, int n_in,
                              void* d_out, int out_size, void* d_ws, size_t ws_size,
                              hipStream_t stream) {
  const float* x = (const float*)d_in[0];     // L*B*D
  const float* W = (const float*)d_in[1];     // K x 3D
  const float* bias = (const float*)d_in[2];  // 2D
  const float* c0 = (const float*)d_in[3];    // B*D
  float* out = (float*)d_out;

  char* ws = (char*)d_ws;
  u16* xb = (u16*)ws;                               // 32 MiB, dead after gemm
  u16* wt = (u16*)(ws + 33554432);                  // 6 MiB
  u16* U = (u16*)(ws + 33554432 + 6291456);         // 96 MiB
  // scan scratch overlaps dead xb region (gemm has consumed xb before phase1 runs)
  float* Aarr = (float*)ws;                         // 1 MiB
  float* Barr = (float*)(ws + 1048576);             // 1 MiB
  float* Cin  = (float*)(ws + 2097152);             // 1 MiB

  cvt_x_kernel<<<16384, 256, 0, stream>>>((const float4*)x, (ushort4*)xb, M_DIM * K_DIM / 4);
  cvt_w_kernel<<<dim3(48, 16), 256, 0, stream>>>(W, wt);
  gemm_kernel<<<dim3(N_DIM / 256, M_DIM / 256), 512, 0, stream>>>(xb, wt, U);
  sru_phase1<<<CHAINS * NCHUNK / 256, 256, 0, stream>>>(U, bias, Aarr, Barr);
  sru_phase2<<<CHAINS / 256, 256, 0, stream>>>(Aarr, Barr, c0, Cin, out + (size_t)M_DIM * D_DIM);
  sru_phase3<<<CHAINS * NCHUNK / 256, 256, 0, stream>>>(U, x, bias, Cin, out);
}